// Round 6
// baseline (1784.785 us; speedup 1.0000x reference)
//
#include <hip/hip_runtime.h>
#include <stdint.h>
#include <math.h>

#define BB 8
#define NN 16384
#define CC 13
#define GG 512
#define KK 32

#define NEIGH_ELEMS (BB*GG*KK*CC)   // 1,703,936

// ---------------------------------------------------------------------------
// Pack: x[B,N,13] (fp32) -> f32 SoA planes px,py,pz (channels 4..6).
// ---------------------------------------------------------------------------
__global__ void pack_kernel(const float* __restrict__ x,
                            float* __restrict__ px, float* __restrict__ py,
                            float* __restrict__ pz) {
    int i = blockIdx.x * blockDim.x + threadIdx.x;
    if (i >= BB * NN) return;
    const float* p = x + (size_t)i * CC + 4;
    px[i] = p[0]; py[i] = p[1]; pz[i] = p[2];
}

// ---------------------------------------------------------------------------
// FPS: one block (512 threads) per batch, 32 points/thread in registers.
// fp32 distance math in reference order ((e0^2+e1^2)+e2^2), NO FMA
// (XLA elementwise+reduce emits separate mul/add). argmax tie -> lowest idx.
// ---------------------------------------------------------------------------
__global__ __launch_bounds__(512, 2) void fps_kernel(const float* __restrict__ px,
                                                     const float* __restrict__ py,
                                                     const float* __restrict__ pz,
                                                     float* __restrict__ centers) {
    const int b = blockIdx.x;
    const int t = threadIdx.x;
    const float* PX = px + b * NN;
    const float* PY = py + b * NN;
    const float* PZ = pz + b * NN;

    float X[32], Y[32], Z[32], MD[32];
#pragma unroll
    for (int i = 0; i < 32; ++i) {
        int pos = t + (i << 9);
        X[i] = PX[pos]; Y[i] = PY[pos]; Z[i] = PZ[pos];
        MD[i] = 1e10f;   // init_d = 10000000000.0
    }

    __shared__ float s_v[8];  __shared__ int s_p[8];
    __shared__ float s_x[8], s_y[8], s_z[8];
    __shared__ float s_bx, s_by, s_bz;

    if (t == 0) {
        s_bx = PX[0]; s_by = PY[0]; s_bz = PZ[0];
        float* oc = centers + (size_t)b * GG * 3;
        oc[0] = s_bx; oc[1] = s_by; oc[2] = s_bz;
    }
    __syncthreads();

    for (int g = 1; g < GG; ++g) {
        float lx = s_bx, ly = s_by, lz = s_bz;
        float bv = -1.0f;
        int bp = 0x7fffffff;
        float bx = 0.f, by = 0.f, bz = 0.f;
#pragma unroll
        for (int i = 0; i < 32; ++i) {
            float e0 = __fsub_rn(X[i], lx);
            float e1 = __fsub_rn(Y[i], ly);
            float e2 = __fsub_rn(Z[i], lz);
            float d  = __fadd_rn(__fadd_rn(__fmul_rn(e0, e0), __fmul_rn(e1, e1)),
                                 __fmul_rn(e2, e2));
            float m = fminf(MD[i], d);   // np.minimum
            MD[i] = m;
            // ascending-index scan + strict '>' keeps lowest index on ties
            if (m > bv) { bv = m; bp = t + (i << 9); bx = X[i]; by = Y[i]; bz = Z[i]; }
        }
        // wave(64) butterfly argmax, tie -> lower index
#pragma unroll
        for (int off = 32; off >= 1; off >>= 1) {
            float ov = __shfl_xor(bv, off);
            int   op = __shfl_xor(bp, off);
            float ox = __shfl_xor(bx, off);
            float oy = __shfl_xor(by, off);
            float oz = __shfl_xor(bz, off);
            if (ov > bv || (ov == bv && op < bp)) { bv = ov; bp = op; bx = ox; by = oy; bz = oz; }
        }
        int w = t >> 6;
        if ((t & 63) == 0) { s_v[w] = bv; s_p[w] = bp; s_x[w] = bx; s_y[w] = by; s_z[w] = bz; }
        __syncthreads();
        if (t == 0) {
            float v = s_v[0]; int p = s_p[0];
            float xx = s_x[0], yy = s_y[0], zz = s_z[0];
            for (int q = 1; q < 8; ++q) {
                float qv = s_v[q]; int qp = s_p[q];
                if (qv > v || (qv == v && qp < p)) { v = qv; p = qp; xx = s_x[q]; yy = s_y[q]; zz = s_z[q]; }
            }
            s_bx = xx; s_by = yy; s_bz = zz;
            float* oc = centers + ((size_t)b * GG + g) * 3;
            oc[0] = xx; oc[1] = yy; oc[2] = zz;
        }
        __syncthreads();
    }
}

// ---------------------------------------------------------------------------
// KNN + gather: one 512-thread block per (b,g) center. fp32 d2 in the
// reference's expansion form:
//   cc,pp: sequential fp32, no FMA (XLA reduce)
//   dot:   Eigen/BLAS-style FMA accumulation: fmaf(c2,p2, fmaf(c1,p1, c0*p0))
//   d2 = (cc+pp) - 2*dot  (fp32, no contraction)
// Each thread owns 32 points + their TOP-2 (d2,pos). 32 extractions via
// butterfly+LDS reduce; owner pops; masked bit-identical recompute only when
// its top-2 is exhausted. Lexicographic (d2,pos) == top_k stable tie-break.
// ---------------------------------------------------------------------------
__global__ __launch_bounds__(512, 2) void knn_kernel(const float* __restrict__ px,
                                                     const float* __restrict__ py,
                                                     const float* __restrict__ pz,
                                                     const float* __restrict__ x,
                                                     const float* __restrict__ centers,
                                                     float* __restrict__ out) {
    const int bg = blockIdx.x;
    const int b  = bg >> 9;
    const int t  = threadIdx.x;

    const float* ctr = centers + (size_t)bg * 3;
    float cx = ctr[0], cy = ctr[1], cz = ctr[2];
    float cc2 = __fadd_rn(__fadd_rn(__fmul_rn(cx, cx), __fmul_rn(cy, cy)),
                          __fmul_rn(cz, cz));

    const float* PX = px + b * NN;
    const float* PY = py + b * NN;
    const float* PZ = pz + b * NN;

    float X[32], Y[32], Z[32];
    float k1 = INFINITY, k2 = INFINITY;
    int   p1 = 0x7fffffff, p2 = 0x7fffffff;
    uint32_t mask = 0;   // consumed elements of my chunk

#pragma unroll
    for (int i = 0; i < 32; ++i) {
        int pos = (i << 9) + t;           // coalesced
        float ax = PX[pos], ay = PY[pos], az = PZ[pos];
        X[i] = ax; Y[i] = ay; Z[i] = az;
        float pp2 = __fadd_rn(__fadd_rn(__fmul_rn(ax, ax), __fmul_rn(ay, ay)),
                              __fmul_rn(az, az));
        float dot = fmaf(cz, az, fmaf(cy, ay, __fmul_rn(cx, ax)));
        float d2  = __fsub_rn(__fadd_rn(cc2, pp2), __fmul_rn(2.0f, dot));
        // ascending pos scan, strict '<': ties keep lower pos
        if (d2 < k1)      { k2 = k1; p2 = p1; k1 = d2; p1 = pos; }
        else if (d2 < k2) { k2 = d2; p2 = pos; }
    }

    __shared__ float s_v[8];
    __shared__ int   s_p[8];
    __shared__ int   s_chosen[KK];
    __shared__ int   s_win;

    for (int j = 0; j < KK; ++j) {
        float v = k1; int vp = p1;
#pragma unroll
        for (int off = 32; off >= 1; off >>= 1) {
            float ov = __shfl_xor(v, off);
            int   op = __shfl_xor(vp, off);
            if (ov < v || (ov == v && op < vp)) { v = ov; vp = op; }
        }
        int w = t >> 6;
        if ((t & 63) == 0) { s_v[w] = v; s_p[w] = vp; }
        __syncthreads();
        if (t == 0) {
            float wv = s_v[0]; int wp = s_p[0];
            for (int q = 1; q < 8; ++q) {
                float qv = s_v[q]; int qp = s_p[q];
                if (qv < wv || (qv == wv && qp < wp)) { wv = qv; wp = qp; }
            }
            s_chosen[j] = wp;
            s_win = wp;
        }
        __syncthreads();
        int wp = s_win;
        if ((wp & 511) == t) {
            // I owned the extracted point: mark consumed, promote second
            mask |= 1u << (wp >> 9);
            k1 = k2; p1 = p2;
            k2 = INFINITY; p2 = 0x7fffffff;
            if (p1 == 0x7fffffff && mask != 0xffffffffu) {
                // top-2 exhausted: rebuild from unmasked points (bit-identical d2)
                k1 = INFINITY;
#pragma unroll
                for (int i = 0; i < 32; ++i) {
                    if ((mask >> i) & 1u) continue;
                    int pos = (i << 9) + t;
                    float ax = X[i], ay = Y[i], az = Z[i];
                    float pp2 = __fadd_rn(__fadd_rn(__fmul_rn(ax, ax), __fmul_rn(ay, ay)),
                                          __fmul_rn(az, az));
                    float dot = fmaf(cz, az, fmaf(cy, ay, __fmul_rn(cx, ax)));
                    float d2  = __fsub_rn(__fadd_rn(cc2, pp2), __fmul_rn(2.0f, dot));
                    if (d2 < k1)      { k2 = k1; p2 = p1; k1 = d2; p1 = pos; }
                    else if (d2 < k2) { k2 = d2; p2 = pos; }
                }
            }
        }
    }
    __syncthreads();

    // gather: 32 neighbors x 13 channels; subtract center from ch 4..6
    if (t < KK * CC) {
        int j = t / CC, c = t - j * CC;
        int pt = s_chosen[j] & (NN - 1);   // safety clamp (no-op when correct)
        float val = x[((size_t)b * NN + pt) * CC + c];
        if (c >= 4 && c < 7) {
            float cs = (c == 4) ? cx : ((c == 5) ? cy : cz);
            val = __fsub_rn(val, cs);
        }
        out[((size_t)bg * KK + j) * CC + c] = val;
    }
}

extern "C" void kernel_launch(void* const* d_in, const int* in_sizes, int n_in,
                              void* d_out, int out_size, void* d_ws, size_t ws_size,
                              hipStream_t stream) {
    const float* x = (const float*)d_in[0];
    float* out = (float*)d_out;
    float* centers = out + NEIGH_ELEMS;   // output 1 follows output 0, flat

    float* px = (float*)d_ws;
    float* py = px + BB * NN;
    float* pz = py + BB * NN;

    pack_kernel<<<(BB * NN + 255) / 256, 256, 0, stream>>>(x, px, py, pz);
    fps_kernel<<<BB, 512, 0, stream>>>(px, py, pz, centers);
    knn_kernel<<<BB * GG, 512, 0, stream>>>(px, py, pz, x, centers, out);
}

// Round 7
// 1752.095 us; speedup vs baseline: 1.0187x; 1.0187x over previous
//
#include <hip/hip_runtime.h>
#include <stdint.h>
#include <math.h>

#define BB 8
#define NN 16384
#define CC 13
#define GG 512
#define KK 32

#define NEIGH_ELEMS (BB*GG*KK*CC)   // 1,703,936

// ---------------------------------------------------------------------------
// Pack: x[B,N,13] (fp32) -> f32 SoA planes px,py,pz (channels 4..6).
// ---------------------------------------------------------------------------
__global__ void pack_kernel(const float* __restrict__ x,
                            float* __restrict__ px, float* __restrict__ py,
                            float* __restrict__ pz) {
    int i = blockIdx.x * blockDim.x + threadIdx.x;
    if (i >= BB * NN) return;
    const float* p = x + (size_t)i * CC + 4;
    px[i] = p[0]; py[i] = p[1]; pz[i] = p[2];
}

// ---------------------------------------------------------------------------
// FPS v2: one block (1024 threads) per batch, 16 points/thread so coords+MD
// (64 VGPRs) stay register-resident under the 128-VGPR cap (R6 post-mortem:
// at 32 pts/thread the compiler rematerialized X/Y/Z loads -> ~3.5k cyc/step
// of L2 traffic). One barrier per step: wave butterfly -> parity-buffered
// partials -> redundant 16-entry scan by every thread. Next-center coords
// come from a same-address broadcast global load (bit-identical to carrying
// them). fp32 math verbatim from R6 (bit-exact vs golden).
// ---------------------------------------------------------------------------
__global__ __launch_bounds__(1024, 4) void fps_kernel(const float* __restrict__ px,
                                                      const float* __restrict__ py,
                                                      const float* __restrict__ pz,
                                                      float* __restrict__ centers) {
    const int b = blockIdx.x;
    const int t = threadIdx.x;
    const float* PX = px + b * NN;
    const float* PY = py + b * NN;
    const float* PZ = pz + b * NN;

    float X[16], Y[16], Z[16], MD[16];
#pragma unroll
    for (int i = 0; i < 16; ++i) {
        int pos = t + (i << 10);
        X[i] = PX[pos]; Y[i] = PY[pos]; Z[i] = PZ[pos];
        MD[i] = 1e10f;   // init_d = 10000000000.0
    }

    __shared__ float s_v[2][16];
    __shared__ int   s_p[2][16];

    int wp = 0;   // current center index (uniform across block)
    if (t == 0) {
        float* oc = centers + (size_t)b * GG * 3;
        oc[0] = PX[0]; oc[1] = PY[0]; oc[2] = PZ[0];
    }

    for (int g = 1; g < GG; ++g) {
        // broadcast load of current center coords (all lanes same address)
        float lx = PX[wp], ly = PY[wp], lz = PZ[wp];
        float bv = -1.0f;
        int bp = 0x7fffffff;
#pragma unroll
        for (int i = 0; i < 16; ++i) {
            float e0 = __fsub_rn(X[i], lx);
            float e1 = __fsub_rn(Y[i], ly);
            float e2 = __fsub_rn(Z[i], lz);
            float d  = __fadd_rn(__fadd_rn(__fmul_rn(e0, e0), __fmul_rn(e1, e1)),
                                 __fmul_rn(e2, e2));
            float m = fminf(MD[i], d);   // np.minimum
            MD[i] = m;
            // ascending-index scan + strict '>' keeps lowest index on ties
            if (m > bv) { bv = m; bp = t + (i << 10); }
        }
        // wave(64) butterfly argmax, tie -> lower flat index
#pragma unroll
        for (int off = 32; off >= 1; off >>= 1) {
            float ov = __shfl_xor(bv, off);
            int   op = __shfl_xor(bp, off);
            if (ov > bv || (ov == bv && op < bp)) { bv = ov; bp = op; }
        }
        int par = g & 1;
        int w = t >> 6;
        if ((t & 63) == 0) { s_v[par][w] = bv; s_p[par][w] = bp; }
        __syncthreads();
        // redundant scan of 16 partials by every thread (LDS broadcast reads)
        float wv = s_v[par][0]; int wi = s_p[par][0];
#pragma unroll
        for (int q = 1; q < 16; ++q) {
            float qv = s_v[par][q]; int qp = s_p[par][q];
            if (qv > wv || (qv == wv && qp < wi)) { wv = qv; wi = qp; }
        }
        wp = wi;
        if (t == 0) {
            float* oc = centers + ((size_t)b * GG + g) * 3;
            oc[0] = PX[wp]; oc[1] = PY[wp]; oc[2] = PZ[wp];
        }
        // no second barrier: parity buffer isolates next round's writes
    }
}

// ---------------------------------------------------------------------------
// KNN v2 + gather: one 256-thread block per (b,g) center, 64 pts/thread.
// No coord registers: only the TOP-2 (d2,pos) cache; rare exhaust-rescan
// reloads from global. d2 math verbatim from R6 (bit-exact): seq-fp32 cc/pp,
// FMA-chain dot, d2=(cc+pp)-2*dot. One barrier per extraction round (parity
// partials + redundant 4-entry scan). Lexicographic (d2,pos) == top_k order.
// ---------------------------------------------------------------------------
__global__ __launch_bounds__(256, 8) void knn_kernel(const float* __restrict__ px,
                                                     const float* __restrict__ py,
                                                     const float* __restrict__ pz,
                                                     const float* __restrict__ x,
                                                     const float* __restrict__ centers,
                                                     float* __restrict__ out) {
    const int bg = blockIdx.x;
    const int b  = bg >> 9;
    const int t  = threadIdx.x;

    const float* ctr = centers + (size_t)bg * 3;
    float cx = ctr[0], cy = ctr[1], cz = ctr[2];
    float cc2 = __fadd_rn(__fadd_rn(__fmul_rn(cx, cx), __fmul_rn(cy, cy)),
                          __fmul_rn(cz, cz));

    const float* PX = px + b * NN;
    const float* PY = py + b * NN;
    const float* PZ = pz + b * NN;

    float k1 = INFINITY, k2 = INFINITY;
    int   p1 = 0x7fffffff, p2 = 0x7fffffff;
    uint64_t mask = 0;   // consumed elements of my 64-pt chunk

#pragma unroll 4
    for (int i = 0; i < 64; ++i) {
        int pos = (i << 8) + t;           // coalesced
        float ax = PX[pos], ay = PY[pos], az = PZ[pos];
        float pp2 = __fadd_rn(__fadd_rn(__fmul_rn(ax, ax), __fmul_rn(ay, ay)),
                              __fmul_rn(az, az));
        float dot = fmaf(cz, az, fmaf(cy, ay, __fmul_rn(cx, ax)));
        float d2  = __fsub_rn(__fadd_rn(cc2, pp2), __fmul_rn(2.0f, dot));
        // ascending pos scan, strict '<': ties keep lower pos
        if (d2 < k1)      { k2 = k1; p2 = p1; k1 = d2; p1 = pos; }
        else if (d2 < k2) { k2 = d2; p2 = pos; }
    }

    __shared__ float s_v[2][4];
    __shared__ int   s_p[2][4];
    __shared__ int   s_chosen[KK];

    for (int j = 0; j < KK; ++j) {
        float v = k1; int vp = p1;
#pragma unroll
        for (int off = 32; off >= 1; off >>= 1) {
            float ov = __shfl_xor(v, off);
            int   op = __shfl_xor(vp, off);
            if (ov < v || (ov == v && op < vp)) { v = ov; vp = op; }
        }
        int par = j & 1;
        int w = t >> 6;
        if ((t & 63) == 0) { s_v[par][w] = v; s_p[par][w] = vp; }
        __syncthreads();
        // redundant scan of 4 partials by every thread
        float wv = s_v[par][0]; int wp = s_p[par][0];
#pragma unroll
        for (int q = 1; q < 4; ++q) {
            float qv = s_v[par][q]; int qp = s_p[par][q];
            if (qv < wv || (qv == wv && qp < wp)) { wv = qv; wp = qp; }
        }
        if (t == 0) s_chosen[j] = wp;
        if ((wp & 255) == t) {
            // I owned the extracted point: mark consumed, promote second
            mask |= 1ull << (wp >> 8);
            k1 = k2; p1 = p2;
            k2 = INFINITY; p2 = 0x7fffffff;
            if (p1 == 0x7fffffff && mask != 0xffffffffffffffffull) {
                // top-2 exhausted (rare): rebuild from unmasked points,
                // reloading coords from global; d2 bit-identical
                k1 = INFINITY;
#pragma unroll 1
                for (int i = 0; i < 64; ++i) {
                    if ((mask >> i) & 1ull) continue;
                    int pos = (i << 8) + t;
                    float ax = PX[pos], ay = PY[pos], az = PZ[pos];
                    float pp2 = __fadd_rn(__fadd_rn(__fmul_rn(ax, ax), __fmul_rn(ay, ay)),
                                          __fmul_rn(az, az));
                    float dot = fmaf(cz, az, fmaf(cy, ay, __fmul_rn(cx, ax)));
                    float d2  = __fsub_rn(__fadd_rn(cc2, pp2), __fmul_rn(2.0f, dot));
                    if (d2 < k1)      { k2 = k1; p2 = p1; k1 = d2; p1 = pos; }
                    else if (d2 < k2) { k2 = d2; p2 = pos; }
                }
            }
        }
        // no second barrier: parity buffer isolates next round's writes
    }
    __syncthreads();   // s_chosen[31] visibility for gather

    // gather: 32 neighbors x 13 channels; subtract center from ch 4..6
    for (int v = t; v < KK * CC; v += 256) {
        int j = v / CC, c = v - j * CC;
        int pt = s_chosen[j] & (NN - 1);   // safety clamp (no-op when correct)
        float val = x[((size_t)b * NN + pt) * CC + c];
        if (c >= 4 && c < 7) {
            float cs = (c == 4) ? cx : ((c == 5) ? cy : cz);
            val = __fsub_rn(val, cs);
        }
        out[((size_t)bg * KK + j) * CC + c] = val;
    }
}

extern "C" void kernel_launch(void* const* d_in, const int* in_sizes, int n_in,
                              void* d_out, int out_size, void* d_ws, size_t ws_size,
                              hipStream_t stream) {
    const float* x = (const float*)d_in[0];
    float* out = (float*)d_out;
    float* centers = out + NEIGH_ELEMS;   // output 1 follows output 0, flat

    float* px = (float*)d_ws;
    float* py = px + BB * NN;
    float* pz = py + BB * NN;

    pack_kernel<<<(BB * NN + 255) / 256, 256, 0, stream>>>(x, px, py, pz);
    fps_kernel<<<BB, 1024, 0, stream>>>(px, py, pz, centers);
    knn_kernel<<<BB * GG, 256, 0, stream>>>(px, py, pz, x, centers, out);
}

// Round 8
// 1452.314 us; speedup vs baseline: 1.2289x; 1.2064x over previous
//
#include <hip/hip_runtime.h>
#include <stdint.h>
#include <math.h>

#define BB 8
#define NN 16384
#define CC 13
#define GG 512
#define KK 32

#define NEIGH_ELEMS (BB*GG*KK*CC)   // 1,703,936

// ---------------------------------------------------------------------------
// Pack: x[B,N,13] (fp32) -> f32 SoA planes px,py,pz (channels 4..6).
// ---------------------------------------------------------------------------
__global__ void pack_kernel(const float* __restrict__ x,
                            float* __restrict__ px, float* __restrict__ py,
                            float* __restrict__ pz) {
    int i = blockIdx.x * blockDim.x + threadIdx.x;
    if (i >= BB * NN) return;
    const float* p = x + (size_t)i * CC + 4;
    px[i] = p[0]; py[i] = p[1]; pz[i] = p[2];
}

// ---------------------------------------------------------------------------
// FPS v3: one block (512 threads) per batch, 32 points/thread, coords PINNED
// in VGPRs via empty asm (R6/R7 post-mortem: compiler rematerialized the
// global loads every step -> ~3K cyc/step of L1 traffic; VGPR_Count 56-100).
// One barrier per step (parity partials, redundant 8-entry scan). Next center
// fetched via scalar loads (readfirstlane). fp32 math verbatim (bit-exact).
// ---------------------------------------------------------------------------
__global__ __launch_bounds__(512, 2) void fps_kernel(const float* __restrict__ px,
                                                     const float* __restrict__ py,
                                                     const float* __restrict__ pz,
                                                     float* __restrict__ centers) {
    const int b = blockIdx.x;
    const int t = threadIdx.x;
    const float* PX = px + b * NN;
    const float* PY = py + b * NN;
    const float* PZ = pz + b * NN;

    float X[32], Y[32], Z[32], MD[32];
#pragma unroll
    for (int i = 0; i < 32; ++i) {
        int pos = t + (i << 9);
        X[i] = PX[pos]; Y[i] = PY[pos]; Z[i] = PZ[pos];
        MD[i] = 1e10f;   // init_d = 10000000000.0
        // Pin: mark values as asm-modified so the loads cannot be
        // rematerialized inside the step loop. Forces VGPR residency.
        asm volatile("" : "+v"(X[i]), "+v"(Y[i]), "+v"(Z[i]));
    }

    __shared__ float s_v[2][8];
    __shared__ int   s_p[2][8];

    int wp = 0;   // current center index (uniform across block)
    if (t == 0) {
        float* oc = centers + (size_t)b * GG * 3;
        oc[0] = PX[0]; oc[1] = PY[0]; oc[2] = PZ[0];
    }

    for (int g = 1; g < GG; ++g) {
        // scalar broadcast load of current center coords (uniform index)
        int swp = __builtin_amdgcn_readfirstlane(wp);
        float lx = PX[swp], ly = PY[swp], lz = PZ[swp];
        float bv = -1.0f;
        int bp = 0x7fffffff;
#pragma unroll
        for (int i = 0; i < 32; ++i) {
            float e0 = __fsub_rn(X[i], lx);
            float e1 = __fsub_rn(Y[i], ly);
            float e2 = __fsub_rn(Z[i], lz);
            float d  = __fadd_rn(__fadd_rn(__fmul_rn(e0, e0), __fmul_rn(e1, e1)),
                                 __fmul_rn(e2, e2));
            float m = fminf(MD[i], d);   // np.minimum
            MD[i] = m;
            // ascending-index scan + strict '>' keeps lowest index on ties
            if (m > bv) { bv = m; bp = t + (i << 9); }
        }
        // wave(64) butterfly argmax, tie -> lower flat index
#pragma unroll
        for (int off = 32; off >= 1; off >>= 1) {
            float ov = __shfl_xor(bv, off);
            int   op = __shfl_xor(bp, off);
            if (ov > bv || (ov == bv && op < bp)) { bv = ov; bp = op; }
        }
        int par = g & 1;
        int w = t >> 6;
        if ((t & 63) == 0) { s_v[par][w] = bv; s_p[par][w] = bp; }
        __syncthreads();
        // redundant scan of 8 partials by every thread (LDS broadcast reads)
        float wv = s_v[par][0]; int wi = s_p[par][0];
#pragma unroll
        for (int q = 1; q < 8; ++q) {
            float qv = s_v[par][q]; int qp = s_p[par][q];
            if (qv > wv || (qv == wv && qp < wi)) { wv = qv; wi = qp; }
        }
        wp = wi;
        if (t == 0) {
            float* oc = centers + ((size_t)b * GG + g) * 3;
            oc[0] = PX[wp]; oc[1] = PY[wp]; oc[2] = PZ[wp];
        }
        // no second barrier: parity buffer isolates next round's writes
    }
}

// ---------------------------------------------------------------------------
// KNN v2 + gather (R7 structure, unchanged math) + XCD swizzle: batch b's 512
// blocks map to one XCD (blockIdx round-robins XCDs by %8) so the 196 KB SoA
// stays L2-resident per XCD.
// ---------------------------------------------------------------------------
__global__ __launch_bounds__(256, 8) void knn_kernel(const float* __restrict__ px,
                                                     const float* __restrict__ py,
                                                     const float* __restrict__ pz,
                                                     const float* __restrict__ x,
                                                     const float* __restrict__ centers,
                                                     float* __restrict__ out) {
    const int blk = blockIdx.x;
    const int bg  = ((blk & 7) << 9) | (blk >> 3);   // batch = blk&7 -> one XCD
    const int b   = bg >> 9;
    const int t   = threadIdx.x;

    const float* ctr = centers + (size_t)bg * 3;
    float cx = ctr[0], cy = ctr[1], cz = ctr[2];
    float cc2 = __fadd_rn(__fadd_rn(__fmul_rn(cx, cx), __fmul_rn(cy, cy)),
                          __fmul_rn(cz, cz));

    const float* PX = px + b * NN;
    const float* PY = py + b * NN;
    const float* PZ = pz + b * NN;

    float k1 = INFINITY, k2 = INFINITY;
    int   p1 = 0x7fffffff, p2 = 0x7fffffff;
    uint64_t mask = 0;   // consumed elements of my 64-pt chunk

#pragma unroll 4
    for (int i = 0; i < 64; ++i) {
        int pos = (i << 8) + t;           // coalesced
        float ax = PX[pos], ay = PY[pos], az = PZ[pos];
        float pp2 = __fadd_rn(__fadd_rn(__fmul_rn(ax, ax), __fmul_rn(ay, ay)),
                              __fmul_rn(az, az));
        float dot = fmaf(cz, az, fmaf(cy, ay, __fmul_rn(cx, ax)));
        float d2  = __fsub_rn(__fadd_rn(cc2, pp2), __fmul_rn(2.0f, dot));
        // ascending pos scan, strict '<': ties keep lower pos
        if (d2 < k1)      { k2 = k1; p2 = p1; k1 = d2; p1 = pos; }
        else if (d2 < k2) { k2 = d2; p2 = pos; }
    }

    __shared__ float s_v[2][4];
    __shared__ int   s_p[2][4];
    __shared__ int   s_chosen[KK];

    for (int j = 0; j < KK; ++j) {
        float v = k1; int vp = p1;
#pragma unroll
        for (int off = 32; off >= 1; off >>= 1) {
            float ov = __shfl_xor(v, off);
            int   op = __shfl_xor(vp, off);
            if (ov < v || (ov == v && op < vp)) { v = ov; vp = op; }
        }
        int par = j & 1;
        int w = t >> 6;
        if ((t & 63) == 0) { s_v[par][w] = v; s_p[par][w] = vp; }
        __syncthreads();
        // redundant scan of 4 partials by every thread
        float wv = s_v[par][0]; int wp = s_p[par][0];
#pragma unroll
        for (int q = 1; q < 4; ++q) {
            float qv = s_v[par][q]; int qp = s_p[par][q];
            if (qv < wv || (qv == wv && qp < wp)) { wv = qv; wp = qp; }
        }
        if (t == 0) s_chosen[j] = wp;
        if ((wp & 255) == t) {
            // I owned the extracted point: mark consumed, promote second
            mask |= 1ull << (wp >> 8);
            k1 = k2; p1 = p2;
            k2 = INFINITY; p2 = 0x7fffffff;
            if (p1 == 0x7fffffff && mask != 0xffffffffffffffffull) {
                // top-2 exhausted (rare): rebuild from unmasked points,
                // reloading coords from global; d2 bit-identical
                k1 = INFINITY;
#pragma unroll 1
                for (int i = 0; i < 64; ++i) {
                    if ((mask >> i) & 1ull) continue;
                    int pos = (i << 8) + t;
                    float ax = PX[pos], ay = PY[pos], az = PZ[pos];
                    float pp2 = __fadd_rn(__fadd_rn(__fmul_rn(ax, ax), __fmul_rn(ay, ay)),
                                          __fmul_rn(az, az));
                    float dot = fmaf(cz, az, fmaf(cy, ay, __fmul_rn(cx, ax)));
                    float d2  = __fsub_rn(__fadd_rn(cc2, pp2), __fmul_rn(2.0f, dot));
                    if (d2 < k1)      { k2 = k1; p2 = p1; k1 = d2; p1 = pos; }
                    else if (d2 < k2) { k2 = d2; p2 = pos; }
                }
            }
        }
        // no second barrier: parity buffer isolates next round's writes
    }
    __syncthreads();   // s_chosen visibility for gather

    // gather: 32 neighbors x 13 channels; subtract center from ch 4..6
    for (int v = t; v < KK * CC; v += 256) {
        int j = v / CC, c = v - j * CC;
        int pt = s_chosen[j] & (NN - 1);   // safety clamp (no-op when correct)
        float val = x[((size_t)b * NN + pt) * CC + c];
        if (c >= 4 && c < 7) {
            float cs = (c == 4) ? cx : ((c == 5) ? cy : cz);
            val = __fsub_rn(val, cs);
        }
        out[((size_t)bg * KK + j) * CC + c] = val;
    }
}

extern "C" void kernel_launch(void* const* d_in, const int* in_sizes, int n_in,
                              void* d_out, int out_size, void* d_ws, size_t ws_size,
                              hipStream_t stream) {
    const float* x = (const float*)d_in[0];
    float* out = (float*)d_out;
    float* centers = out + NEIGH_ELEMS;   // output 1 follows output 0, flat

    float* px = (float*)d_ws;
    float* py = px + BB * NN;
    float* pz = py + BB * NN;

    pack_kernel<<<(BB * NN + 255) / 256, 256, 0, stream>>>(x, px, py, pz);
    fps_kernel<<<BB, 512, 0, stream>>>(px, py, pz, centers);
    knn_kernel<<<BB * GG, 256, 0, stream>>>(px, py, pz, x, centers, out);
}